// Round 4
// baseline (643.011 us; speedup 1.0000x reference)
//
#include <hip/hip_runtime.h>
#include <hip/hip_bf16.h>
#include <cstdint>
#include <cstddef>

// Problem constants (from reference): B=16, H=32, KVH=8, D=128, CACHE=4096
#define BATCH 16
#define HQ 32
#define KVHN 8
#define NREP 4
#define DIM 128
#define CACHE_LEN 4096
#define STATE_POS 64                     // cached positions per partial state (one wave)
#define NSTATE (CACHE_LEN / STATE_POS)   // 64
#define WPB 4                            // waves per block (independent states)

// ---------------------------------------------------------------------------
// Kernel 1: partial flash-decode. 256-thread blocks = 4 INDEPENDENT waves,
// each wave owns one 64-position state (no __syncthreads, no shared state).
// Rationale: 64-thread workgroups capped residency at ~8 waves/CU
// (OccupancyPercent 25, BW 13% — latency-bound). 4 waves/workgroup-slot
// quadruples waves per slot -> ~16 waves/CU at VGPR<=128 -> 2x loads in
// flight.
// Single pass, no softmax-max search: per-state upper bound
//   M_ub[r] = ||q_r/sqrt(D)||_2 * (127*sqrt(128)) * max_s ks[s]
// (Cauchy-Schwarz). exp(sc-M_ub) in [~1e-30,1]; combine rescales exactly.
// Wave layout: 4 groups x 16 lanes; group g handles position s=start+4i+g,
// lane sl owns dims 8*sl..8*sl+7 (2 contiguous int4 = 32B/lane).
// ---------------------------------------------------------------------------
__global__ __launch_bounds__(256, 4) void attn_partial(
    const float* __restrict__ xq,
    const float* __restrict__ fcos,
    const float* __restrict__ fsin,
    const float* __restrict__ k_scaler,
    const float* __restrict__ v_scaler,
    const int*   __restrict__ cache_k,
    const int*   __restrict__ cache_v,
    const int*   __restrict__ input_pos,
    float* __restrict__ ws_acc,   // [B][KVH][NSTATE][4][DIM]
    float* __restrict__ ws_ml)    // [B][KVH][NSTATE][4][2]  (m,l)
{
    const int w     = threadIdx.x >> 6;          // wave id in block
    const int state = blockIdx.x * WPB + w;      // 0..NSTATE-1
    const int kvh   = blockIdx.y;
    const int b     = blockIdx.z;
    const int pos   = input_pos[b];              // cached positions are s < pos
    const int start = state * STATE_POS;
    if (start >= pos) return;                    // whole-wave exit; no barriers used

    const int lane = threadIdx.x & 63;           // 0..63
    const int g    = lane >> 4;                  // position group 0..3
    const int sl   = lane & 15;                  // dim slice
    const int d0   = sl * 8;

    const int send = min(start + STATE_POS, pos);
    const float rsD = 0.088388347648318447f;     // 1/sqrt(128)

    const int bk = b * KVHN + kvh;
    const int*   __restrict__ kb = cache_k + (size_t)bk * CACHE_LEN * DIM;
    const int*   __restrict__ vb = cache_v + (size_t)bk * CACHE_LEN * DIM;
    const float* __restrict__ ks = k_scaler + (size_t)bk * CACHE_LEN;
    const float* __restrict__ vs = v_scaler + (size_t)bk * CACHE_LEN;

    // max k_scaler over this state's positions (always in-bounds reads;
    // reading past send only loosens the bound)
    float ksmax = ks[start + lane];
    #pragma unroll
    for (int mask = 32; mask; mask >>= 1)
        ksmax = fmaxf(ksmax, __shfl_xor(ksmax, mask, 64));

    // RoPE'd q fragment for this lane's 8 dims, pre-scaled by 1/sqrt(D).
    float q[4][8];
    {
        float4 c4 = *(const float4*)(fcos + b * 64 + sl * 4);
        float4 s4 = *(const float4*)(fsin + b * 64 + sl * 4);
        c4.x *= rsD; c4.y *= rsD; c4.z *= rsD; c4.w *= rsD;
        s4.x *= rsD; s4.y *= rsD; s4.z *= rsD; s4.w *= rsD;
        #pragma unroll
        for (int r = 0; r < 4; ++r) {
            const float* qp = xq + ((size_t)(b * HQ + kvh * NREP + r)) * DIM + d0;
            const float4 x0 = *(const float4*)qp;
            const float4 x1 = *(const float4*)(qp + 4);
            q[r][0] = x0.x * c4.x - x0.y * s4.x;
            q[r][1] = x0.x * s4.x + x0.y * c4.x;
            q[r][2] = x0.z * c4.y - x0.w * s4.y;
            q[r][3] = x0.z * s4.y + x0.w * c4.y;
            q[r][4] = x1.x * c4.z - x1.y * s4.z;
            q[r][5] = x1.x * s4.z + x1.y * c4.z;
            q[r][6] = x1.z * c4.w - x1.w * s4.w;
            q[r][7] = x1.z * s4.w + x1.w * c4.w;
        }
    }

    // per-head score upper bound M_ub[r] (wave-uniform)
    float M_ub[4];
    #pragma unroll
    for (int r = 0; r < 4; ++r) {
        float nq = q[r][0]*q[r][0] + q[r][1]*q[r][1] + q[r][2]*q[r][2] + q[r][3]*q[r][3]
                 + q[r][4]*q[r][4] + q[r][5]*q[r][5] + q[r][6]*q[r][6] + q[r][7]*q[r][7];
        #pragma unroll
        for (int mask = 1; mask <= 8; mask <<= 1) nq += __shfl_xor(nq, mask, 64);
        M_ub[r] = sqrtf(nq) * 1436.8398f * ksmax;   // 127*sqrt(128)=1436.84
    }

    float l[4] = {0.f, 0.f, 0.f, 0.f};
    float acc[4][8] = {};

    // ---------------- single fused pass ----------------
    #pragma unroll 4
    for (int i = 0; i < STATE_POS / 4; ++i) {
        const int s = start + i * 4 + g;     // <= 4095 always (addr safe)
        const int* kp = kb + (size_t)s * DIM + d0;
        const int* vp = vb + (size_t)s * DIM + d0;
        const int4 kk0 = *(const int4*)kp;
        const int4 kk1 = *(const int4*)(kp + 4);
        const int4 vv0 = *(const int4*)vp;
        const int4 vv1 = *(const int4*)(vp + 4);
        const float scale = ks[s];
        const float vsc   = vs[s];
        const bool valid  = s < send;

        const float k0 = (float)kk0.x, k1 = (float)kk0.y, k2 = (float)kk0.z, k3 = (float)kk0.w;
        const float k4 = (float)kk1.x, k5 = (float)kk1.y, k6 = (float)kk1.z, k7 = (float)kk1.w;
        float p[4];
        #pragma unroll
        for (int r = 0; r < 4; ++r) {
            p[r] = q[r][0] * k0 + q[r][1] * k1 + q[r][2] * k2 + q[r][3] * k3
                 + q[r][4] * k4 + q[r][5] * k5 + q[r][6] * k6 + q[r][7] * k7;
        }
        #pragma unroll
        for (int mask = 1; mask <= 8; mask <<= 1) {
            #pragma unroll
            for (int r = 0; r < 4; ++r) p[r] += __shfl_xor(p[r], mask, 64);
        }

        const float v0 = (float)vv0.x, v1 = (float)vv0.y, v2 = (float)vv0.z, v3 = (float)vv0.w;
        const float v4 = (float)vv1.x, v5 = (float)vv1.y, v6 = (float)vv1.z, v7 = (float)vv1.w;
        #pragma unroll
        for (int r = 0; r < 4; ++r) {
            float pr = valid ? __expf(p[r] * scale - M_ub[r]) : 0.f;
            l[r] += pr;
            const float pv = pr * vsc;
            acc[r][0] += pv * v0; acc[r][1] += pv * v1;
            acc[r][2] += pv * v2; acc[r][3] += pv * v3;
            acc[r][4] += pv * v4; acc[r][5] += pv * v5;
            acc[r][6] += pv * v6; acc[r][7] += pv * v7;
        }
    }

    // merge the 4 group states: plain sums (M_ub is wave-uniform)
    #pragma unroll
    for (int mask = 16; mask <= 32; mask <<= 1) {
        #pragma unroll
        for (int r = 0; r < 4; ++r) {
            l[r] += __shfl_xor(l[r], mask, 64);
            #pragma unroll
            for (int c = 0; c < 8; ++c) acc[r][c] += __shfl_xor(acc[r][c], mask, 64);
        }
    }

    if (g == 0) {                            // lanes 0..15 hold the totals
        float* abase = ws_acc + (((size_t)bk * NSTATE + state) * 4) * DIM;
        #pragma unroll
        for (int r = 0; r < 4; ++r) {
            float4 a0 = make_float4(acc[r][0], acc[r][1], acc[r][2], acc[r][3]);
            float4 a1 = make_float4(acc[r][4], acc[r][5], acc[r][6], acc[r][7]);
            *(float4*)(abase + r * DIM + d0)     = a0;
            *(float4*)(abase + r * DIM + d0 + 4) = a1;
        }
        if (sl == 0) {
            float* mlb = ws_ml + ((size_t)bk * NSTATE + state) * 8;
            #pragma unroll
            for (int r = 0; r < 4; ++r) { mlb[2 * r] = M_ub[r]; mlb[2 * r + 1] = l[r]; }
        }
    }
}

// ---------------------------------------------------------------------------
// Kernel 2: per-(b,kvh) combine. Recomputes RoPE q, quantizes the new token
// (exactly replicating the reference: max|x|/127+1e-8, round-half-even, clip),
// adds it as one extra softmax state, merges all partials, writes f32 out.
// ---------------------------------------------------------------------------
__global__ __launch_bounds__(256) void attn_combine(
    const float* __restrict__ xq,
    const float* __restrict__ xk,
    const float* __restrict__ xv,
    const float* __restrict__ fcos,
    const float* __restrict__ fsin,
    const int*   __restrict__ input_pos,
    const float* __restrict__ ws_acc,
    const float* __restrict__ ws_ml,
    float* __restrict__ out)
{
    const int bk  = blockIdx.x;
    const int b   = bk >> 3;
    const int kvh = bk & 7;
    const int pos = input_pos[b];
    const int nst = min(NSTATE, (pos + STATE_POS - 1) / STATE_POS);

    const int t    = threadIdx.x;
    const int lane = t & 63;
    const int w    = t >> 6;          // wave id 0..3

    __shared__ float sq[4][DIM];      // RoPE'd q
    __shared__ float skq[DIM];        // rope'd k, then quantized k (int-valued)
    __shared__ float svd[DIM];        // dequantized new v  (v_s * v_q)
    __shared__ float sml[NSTATE][8];  // staged (m,l) per state per head
    __shared__ float ssc[4];          // new-token score per head
    __shared__ float sks, svs;

    const float rsD = 0.088388347648318447f;

    // q RoPE: thread (w=r, lane=p) handles pair p of head r
    {
        const float c  = fcos[b * 64 + lane];
        const float s  = fsin[b * 64 + lane];
        const size_t qb = ((size_t)(b * HQ + kvh * NREP + w)) * DIM;
        const float xe = xq[qb + 2 * lane];
        const float xo = xq[qb + 2 * lane + 1];
        sq[w][2 * lane]     = xe * c - xo * s;
        sq[w][2 * lane + 1] = xe * s + xo * c;
    }
    // k RoPE (wave 0)
    if (w == 0) {
        const float c  = fcos[b * 64 + lane];
        const float s  = fsin[b * 64 + lane];
        const size_t kbb = ((size_t)(b * KVHN + kvh)) * DIM;
        const float xe = xk[kbb + 2 * lane];
        const float xo = xk[kbb + 2 * lane + 1];
        skq[2 * lane]     = xe * c - xo * s;
        skq[2 * lane + 1] = xe * s + xo * c;
    }
    // stage (m,l): only first nst*8 floats are valid in ws
    for (int j = t; j < nst * 8; j += 256)
        sml[j >> 3][j & 7] = ws_ml[(size_t)bk * NSTATE * 8 + j];
    __syncthreads();

    // scalers: k_s from rope'd k (wave 0), v_s from xv (wave 1)
    if (w == 0) {
        float a = fmaxf(fabsf(skq[lane]), fabsf(skq[64 + lane]));
        #pragma unroll
        for (int mask = 32; mask; mask >>= 1) a = fmaxf(a, __shfl_xor(a, mask, 64));
        if (lane == 0) sks = a / 127.0f + 1e-8f;
    } else if (w == 1) {
        const size_t vbb = ((size_t)(b * KVHN + kvh)) * DIM;
        float a = fmaxf(fabsf(xv[vbb + lane]), fabsf(xv[vbb + 64 + lane]));
        #pragma unroll
        for (int mask = 32; mask; mask >>= 1) a = fmaxf(a, __shfl_xor(a, mask, 64));
        if (lane == 0) svs = a / 127.0f + 1e-8f;
    }
    __syncthreads();

    // quantize k, dequantize new v
    if (t < DIM) {
        skq[t] = fminf(fmaxf(rintf(skq[t] / sks), -127.f), 127.f);
    } else {
        const int d = t - DIM;
        const size_t vbb = ((size_t)(b * KVHN + kvh)) * DIM;
        const float vq = fminf(fmaxf(rintf(xv[vbb + d] / svs), -127.f), 127.f);
        svd[d] = vq * svs;
    }
    __syncthreads();

    // new-token score for head w
    {
        float sum = sq[w][lane] * skq[lane] + sq[w][64 + lane] * skq[64 + lane];
        #pragma unroll
        for (int mask = 32; mask; mask >>= 1) sum += __shfl_xor(sum, mask, 64);
        if (lane == 0) ssc[w] = sum * rsD * sks;
    }
    __syncthreads();

    // final combine: thread (w=r, lane=db) handles dims db and db+64
    const int r  = w;
    const int db = lane;
    float M = ssc[r];
    for (int s2 = 0; s2 < nst; ++s2) M = fmaxf(M, sml[s2][2 * r]);
    const float pn = __expf(ssc[r] - M);
    float L  = pn;
    float o0 = pn * svd[db];
    float o1 = pn * svd[db + 64];
    const float* ab = ws_acc + (size_t)bk * NSTATE * 4 * DIM;
    for (int s2 = 0; s2 < nst; ++s2) {
        const float al = __expf(sml[s2][2 * r] - M);
        L  += sml[s2][2 * r + 1] * al;
        o0 += ab[((size_t)(s2 * 4 + r)) * DIM + db]      * al;
        o1 += ab[((size_t)(s2 * 4 + r)) * DIM + db + 64] * al;
    }
    const float invL = 1.0f / L;
    float* ob = out + ((size_t)(b * HQ + kvh * NREP + r)) * DIM;
    ob[db]      = o0 * invL;
    ob[db + 64] = o1 * invL;
}

extern "C" void kernel_launch(void* const* d_in, const int* in_sizes, int n_in,
                              void* d_out, int out_size, void* d_ws, size_t ws_size,
                              hipStream_t stream)
{
    const float* xq        = (const float*)d_in[0];
    const float* xk        = (const float*)d_in[1];
    const float* xv        = (const float*)d_in[2];
    const float* fcos      = (const float*)d_in[3];
    const float* fsin      = (const float*)d_in[4];
    const float* k_scaler  = (const float*)d_in[5];
    const float* v_scaler  = (const float*)d_in[6];
    const int*   cache_k   = (const int*)d_in[7];
    const int*   cache_v   = (const int*)d_in[8];
    const int*   input_pos = (const int*)d_in[9];
    float* out = (float*)d_out;

    float* ws_acc = (float*)d_ws;                                     // 16 MiB
    float* ws_ml  = ws_acc + (size_t)BATCH * KVHN * NSTATE * 4 * DIM; // +256 KiB

    dim3 g1(NSTATE / WPB, KVHN, BATCH);
    attn_partial<<<g1, 64 * WPB, 0, stream>>>(xq, fcos, fsin, k_scaler, v_scaler,
                                              cache_k, cache_v, input_pos, ws_acc, ws_ml);
    attn_combine<<<BATCH * KVHN, 256, 0, stream>>>(xq, xk, xv, fcos, fsin,
                                                   input_pos, ws_acc, ws_ml, out);
}

// Round 5
// 503.146 us; speedup vs baseline: 1.2780x; 1.2780x over previous
//
#include <hip/hip_runtime.h>
#include <hip/hip_bf16.h>
#include <cstdint>
#include <cstddef>

// Problem constants (from reference): B=16, H=32, KVH=8, D=128, CACHE=4096
#define BATCH 16
#define HQ 32
#define KVHN 8
#define NREP 4
#define DIM 128
#define CACHE_LEN 4096
#define STATE_POS 128                    // cached positions per partial state (one wave)
#define NSTATE (CACHE_LEN / STATE_POS)   // 32

// ---------------------------------------------------------------------------
// Kernel 1: per-(b,kvh,state) partial flash-decode over 128 cached positions.
// One wave (64 threads) = 4 groups of 16 lanes. Group g handles position
// s = start + i*4 + g; lane sl owns dims [4sl,4sl+3] and [64+4sl,64+4sl+3].
// DENSE layout: each global_load_dwordx4 instruction covers 4 x 256B fully
// contiguous chunks (one per position) -> 100% cache-line utilization.
// (Round-2's sl*8 stripe was 50% dense -> 2x VMEM transactions; round-4's
// wave packing + launch_bounds(256,4) caused scratch spills: WRITE_SIZE
// 92MB vs 10MB actual. Reverted to 1-wave blocks, no reg cap.)
// Two-pass softmax: K-pass scores -> LDS + running max; V-pass exp + plain
// accumulate (no loop-carried rescale -> loads pipeline freely).
// ---------------------------------------------------------------------------
__global__ __launch_bounds__(64) void attn_partial(
    const float* __restrict__ xq,
    const float* __restrict__ fcos,
    const float* __restrict__ fsin,
    const float* __restrict__ k_scaler,
    const float* __restrict__ v_scaler,
    const int*   __restrict__ cache_k,
    const int*   __restrict__ cache_v,
    const int*   __restrict__ input_pos,
    float* __restrict__ ws_acc,   // [B][KVH][NSTATE][4][DIM]
    float* __restrict__ ws_ml)    // [B][KVH][NSTATE][4][2]  (m,l)
{
    const int state = blockIdx.x;
    const int kvh   = blockIdx.y;
    const int b     = blockIdx.z;
    const int pos   = input_pos[b];          // cached positions are s < pos
    const int start = state * STATE_POS;
    if (start >= pos) return;                // state empty -> combine skips it

    const int lane = threadIdx.x;            // 0..63
    const int g    = lane >> 4;              // position group 0..3
    const int sl   = lane & 15;              // dim slice
    const int dA   = sl * 4;                 // dims dA..dA+3
    const int dB   = 64 + sl * 4;            // dims dB..dB+3

    const int send = min(start + STATE_POS, pos);
    const float rsD = 0.088388347648318447f; // 1/sqrt(128)

    // RoPE'd q fragment for this lane's 8 dims, pre-scaled by 1/sqrt(D).
    // Pair indices: first chunk -> pairs 2sl,2sl+1; second -> 32+2sl,33+2sl.
    float q[4][8];
    {
        float2 cA = *(const float2*)(fcos + b * 64 + 2 * sl);
        float2 sA = *(const float2*)(fsin + b * 64 + 2 * sl);
        float2 cB = *(const float2*)(fcos + b * 64 + 32 + 2 * sl);
        float2 sB = *(const float2*)(fsin + b * 64 + 32 + 2 * sl);
        cA.x *= rsD; cA.y *= rsD; cB.x *= rsD; cB.y *= rsD;
        sA.x *= rsD; sA.y *= rsD; sB.x *= rsD; sB.y *= rsD;
        #pragma unroll
        for (int r = 0; r < 4; ++r) {
            const float* qp = xq + ((size_t)(b * HQ + kvh * NREP + r)) * DIM;
            const float4 x0 = *(const float4*)(qp + dA);
            const float4 x1 = *(const float4*)(qp + dB);
            q[r][0] = x0.x * cA.x - x0.y * sA.x;
            q[r][1] = x0.x * sA.x + x0.y * cA.x;
            q[r][2] = x0.z * cA.y - x0.w * sA.y;
            q[r][3] = x0.z * sA.y + x0.w * cA.y;
            q[r][4] = x1.x * cB.x - x1.y * sB.x;
            q[r][5] = x1.x * sB.x + x1.y * cB.x;
            q[r][6] = x1.z * cB.y - x1.w * sB.y;
            q[r][7] = x1.z * sB.y + x1.w * cB.y;
        }
    }

    const int bk = b * KVHN + kvh;
    const int*   __restrict__ kb = cache_k + (size_t)bk * CACHE_LEN * DIM;
    const int*   __restrict__ vb = cache_v + (size_t)bk * CACHE_LEN * DIM;
    const float* __restrict__ ks = k_scaler + (size_t)bk * CACHE_LEN;
    const float* __restrict__ vs = v_scaler + (size_t)bk * CACHE_LEN;

    __shared__ float4 ssc4[STATE_POS];       // per-position scores, 4 heads

    float mloc[4] = {-1e30f, -1e30f, -1e30f, -1e30f};

    // ---------------- K pass: scores -> LDS, running max ----------------
    #pragma unroll 4
    for (int i = 0; i < STATE_POS / 4; ++i) {
        const int s = start + i * 4 + g;     // always <= 4095 (addr safe)
        const int* kp = kb + (size_t)s * DIM;
        const int4 kk0 = *(const int4*)(kp + dA);
        const int4 kk1 = *(const int4*)(kp + dB);
        const float k0 = (float)kk0.x, k1 = (float)kk0.y, k2 = (float)kk0.z, k3 = (float)kk0.w;
        const float k4 = (float)kk1.x, k5 = (float)kk1.y, k6 = (float)kk1.z, k7 = (float)kk1.w;
        float p[4];
        #pragma unroll
        for (int r = 0; r < 4; ++r) {
            p[r] = q[r][0] * k0 + q[r][1] * k1 + q[r][2] * k2 + q[r][3] * k3
                 + q[r][4] * k4 + q[r][5] * k5 + q[r][6] * k6 + q[r][7] * k7;
        }
        #pragma unroll
        for (int mask = 1; mask <= 8; mask <<= 1) {
            #pragma unroll
            for (int r = 0; r < 4; ++r) p[r] += __shfl_xor(p[r], mask, 64);
        }
        const float scale = ks[s];
        const bool valid = s < send;
        float4 sc;
        sc.x = valid ? p[0] * scale : -1e30f;
        sc.y = valid ? p[1] * scale : -1e30f;
        sc.z = valid ? p[2] * scale : -1e30f;
        sc.w = valid ? p[3] * scale : -1e30f;
        mloc[0] = fmaxf(mloc[0], sc.x);
        mloc[1] = fmaxf(mloc[1], sc.y);
        mloc[2] = fmaxf(mloc[2], sc.z);
        mloc[3] = fmaxf(mloc[3], sc.w);
        if (sl == 0) ssc4[i * 4 + g] = sc;
    }

    // wave-wide max per head (groups differ only across lane bits 4,5)
    #pragma unroll
    for (int r = 0; r < 4; ++r) {
        mloc[r] = fmaxf(mloc[r], __shfl_xor(mloc[r], 16, 64));
        mloc[r] = fmaxf(mloc[r], __shfl_xor(mloc[r], 32, 64));
    }
    __syncthreads();

    // ---------------- V pass: exp + plain accumulate ----------------
    float l[4] = {0.f, 0.f, 0.f, 0.f};
    float acc[4][8] = {};
    #pragma unroll 4
    for (int i = 0; i < STATE_POS / 4; ++i) {
        const int s = start + i * 4 + g;
        const int* vp = vb + (size_t)s * DIM;
        const int4 vv0 = *(const int4*)(vp + dA);
        const int4 vv1 = *(const int4*)(vp + dB);
        const float vsc = vs[s];
        const float4 sc = ssc4[i * 4 + g];   // broadcast within group
        const float v0 = (float)vv0.x, v1 = (float)vv0.y, v2 = (float)vv0.z, v3 = (float)vv0.w;
        const float v4 = (float)vv1.x, v5 = (float)vv1.y, v6 = (float)vv1.z, v7 = (float)vv1.w;
        const float scr[4] = {sc.x, sc.y, sc.z, sc.w};
        #pragma unroll
        for (int r = 0; r < 4; ++r) {
            const float pr = __expf(scr[r] - mloc[r]);  // invalid: exp(-1e30)=0
            l[r] += pr;
            const float pv = pr * vsc;
            acc[r][0] += pv * v0; acc[r][1] += pv * v1;
            acc[r][2] += pv * v2; acc[r][3] += pv * v3;
            acc[r][4] += pv * v4; acc[r][5] += pv * v5;
            acc[r][6] += pv * v6; acc[r][7] += pv * v7;
        }
    }

    // merge the 4 group states: plain sums (max was wave-uniform already)
    #pragma unroll
    for (int mask = 16; mask <= 32; mask <<= 1) {
        #pragma unroll
        for (int r = 0; r < 4; ++r) {
            l[r] += __shfl_xor(l[r], mask, 64);
            #pragma unroll
            for (int c = 0; c < 8; ++c) acc[r][c] += __shfl_xor(acc[r][c], mask, 64);
        }
    }

    if (g == 0) {                            // lanes 0..15 hold the totals
        float* abase = ws_acc + (((size_t)bk * NSTATE + state) * 4) * DIM;
        #pragma unroll
        for (int r = 0; r < 4; ++r) {
            float4 a0 = make_float4(acc[r][0], acc[r][1], acc[r][2], acc[r][3]);
            float4 a1 = make_float4(acc[r][4], acc[r][5], acc[r][6], acc[r][7]);
            *(float4*)(abase + r * DIM + dA) = a0;
            *(float4*)(abase + r * DIM + dB) = a1;
        }
        if (sl == 0) {
            float* mlb = ws_ml + ((size_t)bk * NSTATE + state) * 8;
            #pragma unroll
            for (int r = 0; r < 4; ++r) { mlb[2 * r] = mloc[r]; mlb[2 * r + 1] = l[r]; }
        }
    }
}

// ---------------------------------------------------------------------------
// Kernel 2: per-(b,kvh) combine. Recomputes RoPE q, quantizes the new token
// (exactly replicating the reference: max|x|/127+1e-8, round-half-even, clip),
// adds it as one extra softmax state, merges all partials, writes f32 out.
// ---------------------------------------------------------------------------
__global__ __launch_bounds__(256) void attn_combine(
    const float* __restrict__ xq,
    const float* __restrict__ xk,
    const float* __restrict__ xv,
    const float* __restrict__ fcos,
    const float* __restrict__ fsin,
    const int*   __restrict__ input_pos,
    const float* __restrict__ ws_acc,
    const float* __restrict__ ws_ml,
    float* __restrict__ out)
{
    const int bk  = blockIdx.x;
    const int b   = bk >> 3;
    const int kvh = bk & 7;
    const int pos = input_pos[b];
    const int nst = min(NSTATE, (pos + STATE_POS - 1) / STATE_POS);

    const int t    = threadIdx.x;
    const int lane = t & 63;
    const int w    = t >> 6;          // wave id 0..3

    __shared__ float sq[4][DIM];      // RoPE'd q
    __shared__ float skq[DIM];        // rope'd k, then quantized k (int-valued)
    __shared__ float svd[DIM];        // dequantized new v  (v_s * v_q)
    __shared__ float sml[NSTATE][8];  // staged (m,l) per state per head
    __shared__ float ssc[4];          // new-token score per head
    __shared__ float sks, svs;

    const float rsD = 0.088388347648318447f;

    // q RoPE: thread (w=r, lane=p) handles pair p of head r
    {
        const float c  = fcos[b * 64 + lane];
        const float s  = fsin[b * 64 + lane];
        const size_t qb = ((size_t)(b * HQ + kvh * NREP + w)) * DIM;
        const float xe = xq[qb + 2 * lane];
        const float xo = xq[qb + 2 * lane + 1];
        sq[w][2 * lane]     = xe * c - xo * s;
        sq[w][2 * lane + 1] = xe * s + xo * c;
    }
    // k RoPE (wave 0)
    if (w == 0) {
        const float c  = fcos[b * 64 + lane];
        const float s  = fsin[b * 64 + lane];
        const size_t kbb = ((size_t)(b * KVHN + kvh)) * DIM;
        const float xe = xk[kbb + 2 * lane];
        const float xo = xk[kbb + 2 * lane + 1];
        skq[2 * lane]     = xe * c - xo * s;
        skq[2 * lane + 1] = xe * s + xo * c;
    }
    // stage (m,l): only first nst*8 floats are valid in ws
    for (int j = t; j < nst * 8; j += 256)
        sml[j >> 3][j & 7] = ws_ml[(size_t)bk * NSTATE * 8 + j];
    __syncthreads();

    // scalers: k_s from rope'd k (wave 0), v_s from xv (wave 1)
    if (w == 0) {
        float a = fmaxf(fabsf(skq[lane]), fabsf(skq[64 + lane]));
        #pragma unroll
        for (int mask = 32; mask; mask >>= 1) a = fmaxf(a, __shfl_xor(a, mask, 64));
        if (lane == 0) sks = a / 127.0f + 1e-8f;
    } else if (w == 1) {
        const size_t vbb = ((size_t)(b * KVHN + kvh)) * DIM;
        float a = fmaxf(fabsf(xv[vbb + lane]), fabsf(xv[vbb + 64 + lane]));
        #pragma unroll
        for (int mask = 32; mask; mask >>= 1) a = fmaxf(a, __shfl_xor(a, mask, 64));
        if (lane == 0) svs = a / 127.0f + 1e-8f;
    }
    __syncthreads();

    // quantize k, dequantize new v
    if (t < DIM) {
        skq[t] = fminf(fmaxf(rintf(skq[t] / sks), -127.f), 127.f);
    } else {
        const int d = t - DIM;
        const size_t vbb = ((size_t)(b * KVHN + kvh)) * DIM;
        const float vq = fminf(fmaxf(rintf(xv[vbb + d] / svs), -127.f), 127.f);
        svd[d] = vq * svs;
    }
    __syncthreads();

    // new-token score for head w
    {
        float sum = sq[w][lane] * skq[lane] + sq[w][64 + lane] * skq[64 + lane];
        #pragma unroll
        for (int mask = 32; mask; mask >>= 1) sum += __shfl_xor(sum, mask, 64);
        if (lane == 0) ssc[w] = sum * rsD * sks;
    }
    __syncthreads();

    // final combine: thread (w=r, lane=db) handles dims db and db+64
    const int r  = w;
    const int db = lane;
    float M = ssc[r];
    for (int s2 = 0; s2 < nst; ++s2) M = fmaxf(M, sml[s2][2 * r]);
    const float pn = __expf(ssc[r] - M);
    float L  = pn;
    float o0 = pn * svd[db];
    float o1 = pn * svd[db + 64];
    const float* ab = ws_acc + (size_t)bk * NSTATE * 4 * DIM;
    for (int s2 = 0; s2 < nst; ++s2) {
        const float al = __expf(sml[s2][2 * r] - M);
        L  += sml[s2][2 * r + 1] * al;
        o0 += ab[((size_t)(s2 * 4 + r)) * DIM + db]      * al;
        o1 += ab[((size_t)(s2 * 4 + r)) * DIM + db + 64] * al;
    }
    const float invL = 1.0f / L;
    float* ob = out + ((size_t)(b * HQ + kvh * NREP + r)) * DIM;
    ob[db]      = o0 * invL;
    ob[db + 64] = o1 * invL;
}

extern "C" void kernel_launch(void* const* d_in, const int* in_sizes, int n_in,
                              void* d_out, int out_size, void* d_ws, size_t ws_size,
                              hipStream_t stream)
{
    const float* xq        = (const float*)d_in[0];
    const float* xk        = (const float*)d_in[1];
    const float* xv        = (const float*)d_in[2];
    const float* fcos      = (const float*)d_in[3];
    const float* fsin      = (const float*)d_in[4];
    const float* k_scaler  = (const float*)d_in[5];
    const float* v_scaler  = (const float*)d_in[6];
    const int*   cache_k   = (const int*)d_in[7];
    const int*   cache_v   = (const int*)d_in[8];
    const int*   input_pos = (const int*)d_in[9];
    float* out = (float*)d_out;

    float* ws_acc = (float*)d_ws;                                     // 8 MiB
    float* ws_ml  = ws_acc + (size_t)BATCH * KVHN * NSTATE * 4 * DIM; // +128 KiB

    dim3 g1(NSTATE, KVHN, BATCH);
    attn_partial<<<g1, 64, 0, stream>>>(xq, fcos, fsin, k_scaler, v_scaler,
                                        cache_k, cache_v, input_pos, ws_acc, ws_ml);
    attn_combine<<<BATCH * KVHN, 256, 0, stream>>>(xq, xk, xv, fcos, fsin,
                                                   input_pos, ws_acc, ws_ml, out);
}